// Round 3
// baseline (87.142 us; speedup 1.0000x reference)
//
#include <hip/hip_runtime.h>
#include <math.h>
#include <float.h>

#define EPS 1e-6f
#define THRESHOLD 0.5f

#define NB 16
#define NPOLY 16
#define NVERT 200
#define NSEG_PER_POLY 199
#define NSEG (NPOLY * NSEG_PER_POLY)   // 3184 segments per batch
#define NPTB 300                       // points per batch (10 agents * 30)
#define NPOINTS 4800                   // 16 * 300
#define NSLICE 64
#define SEG_PER_SLICE 50               // ceil(3184/64); last slice has 34

// ---------------------------------------------------------------------------
// Pass 1: per-(batch, segment) precompute (hoists both segment-only divides).
// Entry (2x float4, 32 B): [sx, sy, evx, evy] [inv_esq, slope_eps, ey, 0]
//   slope_eps = (ey-sy)/((ex-sx)+EPS) + EPS  -- identical rounding order to ref
//   inv_esq   = 1/(esq+EPS)                  -- distance path only (ulp-tolerant)
// Also zeroes out[] (poisoned 0xAA before every timed launch).
// ---------------------------------------------------------------------------
__global__ __launch_bounds__(256) void precompute_kernel(
    const float* __restrict__ polys,
    float4* __restrict__ table,
    float* __restrict__ out)
{
    const int idx = blockIdx.x * 256 + threadIdx.x;
    if (idx < 160) out[idx] = 0.0f;
    if (idx >= NB * NSEG) return;

    const int b = idx / NSEG;
    const int s = idx % NSEG;
    const int m = s / NSEG_PER_POLY;
    const int v = s % NSEG_PER_POLY;

    const float2* poly = (const float2*)polys + ((size_t)(b * NPOLY + m) * NVERT);
    const float2 S = poly[v];
    const float2 E = poly[v + 1];

    const float evx = E.x - S.x;
    const float evy = E.y - S.y;
    const float esq = evx * evx + evy * evy;
    const float inv_esq = 1.0f / (esq + EPS);
    const float slope_eps = evy / (evx + EPS) + EPS;  // exact IEEE, ref order

    table[idx * 2]     = make_float4(S.x, S.y, evx, evy);
    table[idx * 2 + 1] = make_float4(inv_esq, slope_eps, E.y, 0.0f);
}

// ---------------------------------------------------------------------------
// Pass 2: lane = point, loop = segment. Segment address is wave-uniform ->
// scalar/broadcast load; segment values become SGPR operands. One block =
// one (batch, segment-slice): 320 threads cover the batch's 300 points.
// Writes per-(slice, point) partials {min_dsq, crossings} to workspace.
// ---------------------------------------------------------------------------
__global__ __launch_bounds__(320) void seg_kernel(
    const float* __restrict__ points,
    const float4* __restrict__ table,
    float* __restrict__ part_dsq,
    int* __restrict__ part_cross)
{
    const int slice = blockIdx.x;       // 0..63
    const int b     = blockIdx.y;       // 0..15
    const int lp    = threadIdx.x;      // 0..319; points 0..299 valid
    const bool active = lp < NPTB;

    const int pidx = b * NPTB + (active ? lp : 0);
    const float2 pt = *(const float2*)(points + (size_t)pidx * 2);
    const float px = pt.x, py = pt.y;

    const float4* tb = table + (size_t)b * NSEG * 2;
    const int s0 = slice * SEG_PER_SLICE;
    const int s1 = (s0 + SEG_PER_SLICE < NSEG) ? s0 + SEG_PER_SLICE : NSEG;

    float min_dsq = FLT_MAX;
    int crossings = 0;

    #pragma unroll 2
    for (int s = s0; s < s1; ++s) {
        // wave-uniform address -> scalar/broadcast load
        const float4 p0 = tb[s * 2];
        const float4 p1 = tb[s * 2 + 1];
        const float sx = p0.x, sy = p0.y, evx = p0.z, evy = p0.w;
        const float inv_esq = p1.x, slope_eps = p1.y, ey = p1.z;

        // ---- point-to-segment squared distance (ulp-tolerant path) ----
        const float v1x = px - sx;
        const float v1y = py - sy;
        const float dot = v1x * evx + v1y * evy;
        float t = dot * inv_esq;
        t = fminf(fmaxf(t, 0.0f), 1.0f);
        const float dx = px - (evx * t + sx);
        const float dy = py - (evy * t + sy);
        const float dsq = dx * dx + dy * dy;
        min_dsq = fminf(min_dsq, dsq);

        // ---- even-odd crossing (bit-exact path) ----
        // (sy<=py & py<ey)|(ey<=py & py<sy)  ==  (sy<=py) XOR (ey<=py)
        const bool cond_y = (sy <= py) != (ey <= py);
        const float ix = sx + v1y / slope_eps;  // exact IEEE div, ref op order
        crossings += (cond_y && (ix > px)) ? 1 : 0;
    }

    if (active) {
        const int o = slice * NPOINTS + pidx;
        part_dsq[o]   = min_dsq;
        part_cross[o] = crossings;
    }
}

// ---------------------------------------------------------------------------
// Pass 3: per-point reduction over 64 slices + epilogue + atomic into out.
// ---------------------------------------------------------------------------
__global__ __launch_bounds__(256) void final_kernel(
    const float* __restrict__ part_dsq,
    const int* __restrict__ part_cross,
    float* __restrict__ out)
{
    const int p = blockIdx.x * 256 + threadIdx.x;
    if (p >= NPOINTS) return;

    float md = FLT_MAX;
    int c = 0;
    #pragma unroll 8
    for (int k = 0; k < NSLICE; ++k) {
        md = fminf(md, part_dsq[k * NPOINTS + p]);
        c += part_cross[k * NPOINTS + p];
    }

    float d = sqrtf(fmaxf(md, EPS));
    if (c & 1) d = -d;
    const float val = fmaxf(d + THRESHOLD, 0.0f);

    const int b = p / NPTB;
    const int a = (p % NPTB) / 30;
    atomicAdd(out + b * 10 + a, val);
}

extern "C" void kernel_launch(void* const* d_in, const int* in_sizes, int n_in,
                              void* d_out, int out_size, void* d_ws, size_t ws_size,
                              hipStream_t stream) {
    const float* points = (const float*)d_in[0];   // (16,10,30,2)
    const float* polys  = (const float*)d_in[1];   // (16,16,200,2)
    float* out = (float*)d_out;                    // (16,10)

    char* ws = (char*)d_ws;
    float4* table     = (float4*)ws;               // 16*3184*32 B = 1.63 MB
    float*  part_dsq  = (float*)(ws + (2u << 20)); // 64*4800*4 B = 1.2 MB
    int*    part_cross= (int*)  (ws + (4u << 20)); // 64*4800*4 B = 1.2 MB

    const int n_entries = NB * NSEG;               // 50944
    precompute_kernel<<<(n_entries + 255) / 256, 256, 0, stream>>>(polys, table, out);

    dim3 grid(NSLICE, NB);                         // 64 x 16 = 1024 blocks
    seg_kernel<<<grid, 320, 0, stream>>>(points, table, part_dsq, part_cross);

    final_kernel<<<(NPOINTS + 255) / 256, 256, 0, stream>>>(part_dsq, part_cross, out);
}

// Round 4
// 82.947 us; speedup vs baseline: 1.0506x; 1.0506x over previous
//
#include <hip/hip_runtime.h>
#include <math.h>
#include <float.h>

#define EPS 1e-6f
#define THRESHOLD 0.5f

#define NB 16
#define NPOLY 16
#define NVERT 200
#define NSEG_PER_POLY 199
#define NSEG (NPOLY * NSEG_PER_POLY)   // 3184 segments per batch
#define NPTB 300                       // points per batch (10 agents * 30)
#define NPOINTS 4800                   // 16 * 300
#define NSLICE 64
#define SEG_PER_SLICE 50               // slices 0..62: 50 segs, slice 63: 34

// ---------------------------------------------------------------------------
// Fused kernel: one block per (batch, segment-slice).
//  Prologue: threads 0..nseg-1 precompute their segment (2 divides hoisted)
//            into LDS — each (b,slice) is owned by exactly one block, so no
//            duplicated precompute work, and no global table round-trip.
//  Main loop: lane = point (300 of 320 threads), wave-uniform ds_read_b128
//            broadcast of the segment from LDS; ONE IEEE div per eval
//            (crossing test — must stay bit-exact vs numpy ref).
//  Epilogue: per-(slice,point) partials to ws; slice-0 idle lanes zero out[].
// Exactness notes:
//   slope_eps = (ey-sy)/((ex-sx)+EPS) + EPS  -- identical rounding order to ref
//   inv_esq   = 1/(esq+EPS)                  -- distance path only (ulp-tolerant)
//   cond_y: (sy<=py & py<ey)|(ey<=py & py<sy) == (sy<=py) XOR (ey<=py), exact.
// ---------------------------------------------------------------------------
__global__ __launch_bounds__(320) void seg_kernel(
    const float* __restrict__ points,
    const float* __restrict__ polys,
    float* __restrict__ part_dsq,
    int* __restrict__ part_cross,
    float* __restrict__ out)
{
    __shared__ float4 lds[SEG_PER_SLICE * 2];

    const int slice = blockIdx.x;       // 0..63
    const int b     = blockIdx.y;       // 0..15
    const int lp    = threadIdx.x;      // 0..319; points 0..299 valid
    const bool active = lp < NPTB;

    const int s0 = slice * SEG_PER_SLICE;
    const int s1 = (s0 + SEG_PER_SLICE < NSEG) ? s0 + SEG_PER_SLICE : NSEG;
    const int nseg = s1 - s0;

    // ---- prologue: per-segment precompute into LDS ----
    if (lp < nseg) {
        const int s = s0 + lp;
        const int m = s / NSEG_PER_POLY;
        const int v = s % NSEG_PER_POLY;
        const float2* poly = (const float2*)polys + ((size_t)(b * NPOLY + m) * NVERT);
        const float2 S = poly[v];
        const float2 E = poly[v + 1];
        const float evx = E.x - S.x;
        const float evy = E.y - S.y;
        const float esq = evx * evx + evy * evy;
        const float inv_esq = 1.0f / (esq + EPS);
        const float slope_eps = evy / (evx + EPS) + EPS;  // exact IEEE, ref order
        lds[lp * 2]     = make_float4(S.x, S.y, evx, evy);
        lds[lp * 2 + 1] = make_float4(inv_esq, slope_eps, E.y, 0.0f);
    }
    __syncthreads();

    const int pidx = b * NPTB + (active ? lp : 0);
    const float2 pt = *(const float2*)(points + (size_t)pidx * 2);
    const float px = pt.x, py = pt.y;

    float min_dsq = FLT_MAX;
    int crossings = 0;

    #pragma unroll 2
    for (int j = 0; j < nseg; ++j) {
        // wave-uniform LDS address -> broadcast read, conflict-free
        const float4 p0 = lds[j * 2];
        const float4 p1 = lds[j * 2 + 1];
        const float sx = p0.x, sy = p0.y, evx = p0.z, evy = p0.w;
        const float inv_esq = p1.x, slope_eps = p1.y, ey = p1.z;

        // ---- point-to-segment squared distance (ulp-tolerant path) ----
        const float v1x = px - sx;
        const float v1y = py - sy;
        const float dot = v1x * evx + v1y * evy;
        float t = dot * inv_esq;
        t = fminf(fmaxf(t, 0.0f), 1.0f);
        const float dx = px - (evx * t + sx);
        const float dy = py - (evy * t + sy);
        const float dsq = dx * dx + dy * dy;
        min_dsq = fminf(min_dsq, dsq);

        // ---- even-odd crossing (bit-exact path) ----
        const bool cond_y = (sy <= py) != (ey <= py);
        const float ix = sx + v1y / slope_eps;  // exact IEEE div, ref op order
        crossings += (cond_y && (ix > px)) ? 1 : 0;
    }

    if (active) {
        const int o = slice * NPOINTS + pidx;
        part_dsq[o]   = min_dsq;
        part_cross[o] = crossings;
    } else if (slice == 0 && lp >= NPTB && lp < NPTB + 10) {
        // zero out[] (poisoned 0xAA); final_kernel's atomics run after this
        // kernel completes (stream order), so this is race-free.
        out[b * 10 + (lp - NPTB)] = 0.0f;
    }
}

// ---------------------------------------------------------------------------
// Per-point reduction over 64 slices + epilogue + atomic into out.
// ---------------------------------------------------------------------------
__global__ __launch_bounds__(256) void final_kernel(
    const float* __restrict__ part_dsq,
    const int* __restrict__ part_cross,
    float* __restrict__ out)
{
    const int p = blockIdx.x * 256 + threadIdx.x;
    if (p >= NPOINTS) return;

    float md = FLT_MAX;
    int c = 0;
    #pragma unroll 8
    for (int k = 0; k < NSLICE; ++k) {
        md = fminf(md, part_dsq[k * NPOINTS + p]);
        c += part_cross[k * NPOINTS + p];
    }

    float d = sqrtf(fmaxf(md, EPS));
    if (c & 1) d = -d;
    const float val = fmaxf(d + THRESHOLD, 0.0f);

    const int b = p / NPTB;
    const int a = (p % NPTB) / 30;
    atomicAdd(out + b * 10 + a, val);
}

extern "C" void kernel_launch(void* const* d_in, const int* in_sizes, int n_in,
                              void* d_out, int out_size, void* d_ws, size_t ws_size,
                              hipStream_t stream) {
    const float* points = (const float*)d_in[0];   // (16,10,30,2)
    const float* polys  = (const float*)d_in[1];   // (16,16,200,2)
    float* out = (float*)d_out;                    // (16,10)

    char* ws = (char*)d_ws;
    float* part_dsq   = (float*)ws;                // 64*4800*4 B = 1.2 MB
    int*   part_cross = (int*)(ws + (2u << 20));   // 64*4800*4 B = 1.2 MB

    dim3 grid(NSLICE, NB);                         // 64 x 16 = 1024 blocks
    seg_kernel<<<grid, 320, 0, stream>>>(points, polys, part_dsq, part_cross, out);
    final_kernel<<<(NPOINTS + 255) / 256, 256, 0, stream>>>(part_dsq, part_cross, out);
}

// Round 5
// 81.559 us; speedup vs baseline: 1.0685x; 1.0170x over previous
//
#include <hip/hip_runtime.h>
#include <math.h>
#include <float.h>

#define EPS 1e-6f
#define THRESHOLD 0.5f

#define NB 16
#define NPOLY 16
#define NVERT 200
#define NSEG_PER_POLY 199
#define NSEG (NPOLY * NSEG_PER_POLY)   // 3184 segments per batch
#define NPTB 300                       // points per batch (10 agents * 30)
#define NPOINTS 4800                   // 16 * 300
#define NSLICE 64
#define SEG_PER_SLICE 50               // slices 0..62: 50 segs, slice 63: 34

// ---------------------------------------------------------------------------
// Fused kernel: one block per (batch, segment-slice).
//  Prologue: threads 0..nseg-1 precompute their segment into LDS (2 divides
//            + 1 rcp hoisted; each (b,slice) owned by exactly one block).
//  Main loop: lane = point; wave-uniform ds_read_b128 broadcasts; crossing
//            test uses rcp fast path with EXACT-div fallback only when the
//            approximate intersect-x is within ~8 ulp of px — so the
//            inside-parity decision always bit-matches the numpy reference.
// Entry (2x float4): [sx, sy, evx, evy] [inv_esq, slope_eps, inv_slope, ey]
//   slope_eps = (ey-sy)/((ex-sx)+EPS) + EPS  -- identical rounding order to ref
//   inv_esq   = 1/(esq+EPS)                  -- distance path only (ulp-tolerant)
//   inv_slope = v_rcp_f32(slope_eps)         -- fast-path only
// ---------------------------------------------------------------------------
__global__ __launch_bounds__(320) void seg_kernel(
    const float* __restrict__ points,
    const float* __restrict__ polys,
    float* __restrict__ part_dsq,
    int* __restrict__ part_cross,
    float* __restrict__ out)
{
    __shared__ float4 lds[SEG_PER_SLICE * 2];

    const int slice = blockIdx.x;       // 0..63
    const int b     = blockIdx.y;       // 0..15
    const int lp    = threadIdx.x;      // 0..319; points 0..299 valid
    const bool active = lp < NPTB;

    const int s0 = slice * SEG_PER_SLICE;
    const int s1 = (s0 + SEG_PER_SLICE < NSEG) ? s0 + SEG_PER_SLICE : NSEG;
    const int nseg = s1 - s0;

    // ---- prologue: per-segment precompute into LDS ----
    if (lp < nseg) {
        const int s = s0 + lp;
        const int m = s / NSEG_PER_POLY;
        const int v = s % NSEG_PER_POLY;
        const float2* poly = (const float2*)polys + ((size_t)(b * NPOLY + m) * NVERT);
        const float2 S = poly[v];
        const float2 E = poly[v + 1];
        const float evx = E.x - S.x;
        const float evy = E.y - S.y;
        const float esq = evx * evx + evy * evy;
        const float inv_esq = 1.0f / (esq + EPS);
        const float slope_eps = evy / (evx + EPS) + EPS;  // exact IEEE, ref order
        const float inv_slope = __builtin_amdgcn_rcpf(slope_eps);
        lds[lp * 2]     = make_float4(S.x, S.y, evx, evy);
        lds[lp * 2 + 1] = make_float4(inv_esq, slope_eps, inv_slope, E.y);
    }
    __syncthreads();

    const int pidx = b * NPTB + (active ? lp : 0);
    const float2 pt = *(const float2*)(points + (size_t)pidx * 2);
    const float px = pt.x, py = pt.y;

    float min_dsq = FLT_MAX;
    int crossings = 0;

    #pragma unroll 2
    for (int j = 0; j < nseg; ++j) {
        // wave-uniform LDS address -> broadcast read, conflict-free
        const float4 p0 = lds[j * 2];
        const float4 p1 = lds[j * 2 + 1];
        const float sx = p0.x, sy = p0.y, evx = p0.z, evy = p0.w;
        const float inv_esq = p1.x, slope_eps = p1.y, inv_slope = p1.z, ey = p1.w;

        // ---- point-to-segment squared distance (ulp-tolerant path) ----
        const float v1x = px - sx;
        const float v1y = py - sy;
        const float dot = v1x * evx + v1y * evy;
        float t = dot * inv_esq;
        t = fminf(fmaxf(t, 0.0f), 1.0f);
        const float dx = px - (evx * t + sx);
        const float dy = py - (evy * t + sy);
        const float dsq = dx * dx + dy * dy;
        min_dsq = fminf(min_dsq, dsq);

        // ---- even-odd crossing: rcp fast path + exact-div fallback ----
        // (sy<=py & py<ey)|(ey<=py & py<sy)  ==  (sy<=py) XOR (ey<=py)
        const bool cond_y = (sy <= py) != (ey <= py);
        const float q    = v1y * inv_slope;     // ~3 ulp vs exact quotient
        const float ixa  = sx + q;
        const float diff = ixa - px;
        // certainty bound: ~8 ulp relative + denormal guard
        const float err  = fmaf(fabsf(q) + fabsf(ixa), 1e-6f, 1e-30f);
        bool left = diff > 0.0f;
        if (cond_y && !(fabsf(diff) > err)) {
            // rare (~1e-6 of evals): decision within noise — replicate ref
            // bit-exactly: IEEE div, same operand order.
            left = (sx + v1y / slope_eps) > px;
        }
        crossings += (cond_y && left) ? 1 : 0;
    }

    if (active) {
        const int o = slice * NPOINTS + pidx;
        part_dsq[o]   = min_dsq;
        part_cross[o] = crossings;
    } else if (slice == 0 && lp >= NPTB && lp < NPTB + 10) {
        // zero out[] (poisoned 0xAA); final_kernel's atomics run after this
        // kernel completes (stream order), so this is race-free.
        out[b * 10 + (lp - NPTB)] = 0.0f;
    }
}

// ---------------------------------------------------------------------------
// Per-point reduction over 64 slices + epilogue + atomic into out.
// ---------------------------------------------------------------------------
__global__ __launch_bounds__(256) void final_kernel(
    const float* __restrict__ part_dsq,
    const int* __restrict__ part_cross,
    float* __restrict__ out)
{
    const int p = blockIdx.x * 256 + threadIdx.x;
    if (p >= NPOINTS) return;

    float md = FLT_MAX;
    int c = 0;
    #pragma unroll 8
    for (int k = 0; k < NSLICE; ++k) {
        md = fminf(md, part_dsq[k * NPOINTS + p]);
        c += part_cross[k * NPOINTS + p];
    }

    float d = sqrtf(fmaxf(md, EPS));
    if (c & 1) d = -d;
    const float val = fmaxf(d + THRESHOLD, 0.0f);

    const int b = p / NPTB;
    const int a = (p % NPTB) / 30;
    atomicAdd(out + b * 10 + a, val);
}

extern "C" void kernel_launch(void* const* d_in, const int* in_sizes, int n_in,
                              void* d_out, int out_size, void* d_ws, size_t ws_size,
                              hipStream_t stream) {
    const float* points = (const float*)d_in[0];   // (16,10,30,2)
    const float* polys  = (const float*)d_in[1];   // (16,16,200,2)
    float* out = (float*)d_out;                    // (16,10)

    char* ws = (char*)d_ws;
    float* part_dsq   = (float*)ws;                // 64*4800*4 B = 1.2 MB
    int*   part_cross = (int*)(ws + (2u << 20));   // 64*4800*4 B = 1.2 MB

    dim3 grid(NSLICE, NB);                         // 64 x 16 = 1024 blocks
    seg_kernel<<<grid, 320, 0, stream>>>(points, polys, part_dsq, part_cross, out);
    final_kernel<<<(NPOINTS + 255) / 256, 256, 0, stream>>>(part_dsq, part_cross, out);
}